// Round 8
// baseline (155.113 us; speedup 1.0000x reference)
//
#include <hip/hip_runtime.h>

// retinex_synthesis, SINGLE-kernel rolling separable blur.
// out = clip((1+ins)*exp2(blur(log2(1+bg) - log2(1+ins))) - 1, 0, 1)
//
// R13 = R12 wave-specialized structure, but ALL barriers are plain
// __syncthreads(). R12 (custom lgkmcnt-only barrier + specialization)
// ABORTED at runtime; R9 showed the custom barrier is perf-NEUTRAL vs
// __syncthreads, so it carries risk with no reward -> removed. One
// variable changed vs the crashed version.
//
// Structure: phase 2 runs h-blur(k) and emit(k-2) CONCURRENTLY on
// disjoint waves (R11 ran them serially; all pipes were <=40% busy):
//   emit(k-2) reads ring rows [32k-79, 32k-18]
//   h-blur(k) writes         [32k-15, 32k+16]
// Disjoint in a 96-slot ring: write-read logical distance spans [3,95],
// never 0 mod 96. Waves 0-1 h-blur (32 rows x 4 col-groups of 16), waves
// 2-3 emit (2 row-groups of 16 x 64 lanes). All 256 threads stage.
// Fatter per-thread windows also cut LDS read count ~32%.
// Hazards: stage(k)->barA->hblur(k) RAW; hblur(k) sd reads ->barB->
// stage(k+1) WAR; emit reads vs hblur(k+1) ring writes separated by
// barB+barA. All enforced by __syncthreads.
// Ring mod-96 via conditional subtracts; emit row base wave-uniform
// (readfirstlane) -> SALU. LDS = 12.8 + 26.1 = 38.9 KB -> 3 blocks/CU.
// Iterations 10 (emit lags 2). Epilogue identity: (1+ins)*exp2(acc)-1.
// Blur FMAs packed (R11): v_pk_fma_f32 via <2 x float> fma, zero-padded
// compile-time coefficient pairs, per-output accumulation order preserved.

constexpr int W_ = 512, H_ = 512, NIMG = 48;
constexpr int SPITCH = 100;  // staging pitch: 96 cols + 4; 25 slots, 25%8==1
constexpr int RPITCH = 68;   // ring pitch: 64 cols + 4
constexpr int RSLOTS = 96;   // ring rows (logical row mod 96)

typedef float v2f __attribute__((ext_vector_type(2)));

__device__ constexpr float G[31] = {
    8.8805851e-04f, 1.5861066e-03f, 2.7217699e-03f, 4.4874399e-03f,
    7.1084368e-03f, 1.0818767e-02f, 1.5820117e-02f, 2.2226435e-02f,
    3.0002549e-02f, 3.8911209e-02f, 4.8486352e-02f, 5.8048702e-02f,
    6.6771901e-02f, 7.3794364e-02f, 7.8357552e-02f, 7.9940480e-02f,
    7.8357552e-02f, 7.3794364e-02f, 6.6771901e-02f, 5.8048702e-02f,
    4.8486352e-02f, 3.8911209e-02f, 3.0002549e-02f, 2.2226435e-02f,
    1.5820117e-02f, 1.0818767e-02f, 7.1084368e-03f, 4.4874399e-03f,
    2.7217699e-03f, 1.5861066e-03f, 8.8805851e-04f};

// Zero-padded coefficient: compile-time c -> literal (0 outside [0,31)).
__device__ constexpr float gc(int c) { return (c >= 0 && c < 31) ? G[c] : 0.f; }

__global__ __launch_bounds__(256, 3) void retinex_roll(const float* __restrict__ bg,
                                                       const float* __restrict__ ins,
                                                       float* __restrict__ out) {
  __shared__ __align__(16) float sd[32 * SPITCH];     // 12,800 B: staged d chunk
  __shared__ __align__(16) float hr[RSLOTS * RPITCH]; // 26,112 B: h-blurred ring

  const int tid  = threadIdx.x;
  const int x0 = blockIdx.x * 64;
  const int y0 = blockIdx.y * 256;
  const size_t base = (size_t)blockIdx.z * (size_t)(H_ * W_);

  // Staging geometry (k-invariant): 768 float4 items = 32 rows x 24 slots.
  int sr[3], sc[3], gx[3]; bool okx[3];
#pragma unroll
  for (int s = 0; s < 3; ++s) {
    const int item = tid + 256 * s;
    sr[s] = item / 24;
    sc[s] = item - 24 * sr[s];
    gx[s] = x0 - 16 + 4 * sc[s];          // float4-aligned; OOB is whole-float4
    okx[s] = (unsigned)gx[s] < (unsigned)W_;
  }
  // Role split (wave-uniform): waves 0-1 h-blur, waves 2-3 emit.
  const bool is_h = (tid < 128);
  const int hrow = tid >> 2;              // h: staged row 0..31 (tid<128)
  const int hc16 = tid & 3;               // h: col group (16 cols each)
  const int et    = tid & 127;            // e: emit-thread 0..127
  const int elane = et & 63;              // e: column
  const int eg = __builtin_amdgcn_readfirstlane(et >> 6);  // e: row-group 0..1

  // Initial prefetch: chunk 0 = rows y0-15 .. y0+16.
  float4 pb[3], pn[3];
#pragma unroll
  for (int s = 0; s < 3; ++s) {
    const int gy = y0 - 15 + sr[s];
    pb[s] = make_float4(0.f, 0.f, 0.f, 0.f);
    pn[s] = pb[s];
    if (okx[s] && (unsigned)gy < (unsigned)H_) {
      const size_t a = base + (size_t)gy * W_ + gx[s];
      pb[s] = *(const float4*)(bg + a);
      pn[s] = *(const float4*)(ins + a);
    }
  }

#pragma unroll 1
  for (int k = 0; k < 10; ++k) {
    // ---- P1: stage chunk k (all threads): d2 = log2(1+bg)-log2(1+ins).
    if (k <= 8) {
#pragma unroll
      for (int s = 0; s < 3; ++s) {
        float4 v;
        v.x = __builtin_amdgcn_logf(1.f + pb[s].x) - __builtin_amdgcn_logf(1.f + pn[s].x);
        v.y = __builtin_amdgcn_logf(1.f + pb[s].y) - __builtin_amdgcn_logf(1.f + pn[s].y);
        v.z = __builtin_amdgcn_logf(1.f + pb[s].z) - __builtin_amdgcn_logf(1.f + pn[s].z);
        v.w = __builtin_amdgcn_logf(1.f + pb[s].w) - __builtin_amdgcn_logf(1.f + pn[s].w);
        *(float4*)(sd + sr[s] * SPITCH + 4 * sc[s]) = v;
      }
    }
    // ---- Prefetch chunk k+1 (in flight until next iteration's stage).
    if (k <= 7) {
#pragma unroll
      for (int s = 0; s < 3; ++s) {
        const int gy = y0 + 32 * (k + 1) - 15 + sr[s];
        float4 b0 = make_float4(0.f, 0.f, 0.f, 0.f), n0 = b0;
        if (okx[s] && (unsigned)gy < (unsigned)H_) {
          const size_t a = base + (size_t)gy * W_ + gx[s];
          b0 = *(const float4*)(bg + a);
          n0 = *(const float4*)(ins + a);
        }
        pb[s] = b0; pn[s] = n0;
      }
    }
    __syncthreads();   // A: sd ready; orders prev emit reads vs this h-blur writes

    // ---- P2: h-blur(k) on waves 0-1  ||  emit(k-2) on waves 2-3.
    if (is_h) {
      if (k <= 8) {
        // 16 output cols per thread: cols 16*hc16 .. +15 of staged row hrow.
        v2f o2[8];
#pragma unroll
        for (int m = 0; m < 8; ++m) o2[m] = (v2f){0.f, 0.f};
        const float4* p4 = (const float4*)(sd + hrow * SPITCH) + hc16 * 4;
#pragma unroll
        for (int q = 0; q < 12; ++q) {     // window: staged cols 16hc16..+47
          const float4 v = p4[q];
          const float w4[4] = {v.x, v.y, v.z, v.w};
#pragma unroll
          for (int t = 0; t < 4; ++t) {
            const int w = 4 * q + t;
            const v2f vv = {w4[t], w4[t]};
#pragma unroll
            for (int m = 0; m < 8; ++m) {
              const int c0 = w - 1 - 2 * m;   // compile-time
              if (c0 >= 0 && c0 < 32) {
                const v2f kc = {gc(c0), gc(c0 - 1)};
                o2[m] = __builtin_elementwise_fma(vv, kc, o2[m]);
              }
            }
          }
        }
        // slot = (32k - 15 + hrow) mod 96
        int u = 32 * k + 81 + hrow;          // [81, 368]
        u -= (u >= 192) ? 192 : 0;           // [0, 191]
        u -= (u >= 96) ? 96 : 0;             // [0, 95]
        float* dst = hr + u * RPITCH + 16 * hc16;
        *(float4*)(dst +  0) = make_float4(o2[0].x, o2[0].y, o2[1].x, o2[1].y);
        *(float4*)(dst +  4) = make_float4(o2[2].x, o2[2].y, o2[3].x, o2[3].y);
        *(float4*)(dst +  8) = make_float4(o2[4].x, o2[4].y, o2[5].x, o2[5].y);
        *(float4*)(dst + 12) = make_float4(o2[6].x, o2[6].y, o2[7].x, o2[7].y);
      }
    } else if (k >= 2) {
      // 16 output rows per thread: rows t0..t0+15, col elane.
      const int t0 = 32 * (k - 2) + 16 * eg;   // scalar
      int eb = t0 + 81;                        // (t0-15) mod 96: [81, 321]
      eb -= (eb >= 192) ? 192 : 0;
      eb -= (eb >= 96) ? 96 : 0;               // [0, 95]
      // Epilogue ins loads issued early; latency hides under v-blur.
      float insv[16];
#pragma unroll
      for (int p = 0; p < 16; ++p)
        insv[p] = ins[base + (size_t)(y0 + t0 + p) * W_ + x0 + elane];
      v2f acc2[8];
#pragma unroll
      for (int m = 0; m < 8; ++m) acc2[m] = (v2f){0.f, 0.f};
#pragma unroll
      for (int j = 0; j < 46; ++j) {           // h-rows t0-15 .. t0+30
        int row = eb + j;                      // scalar (SALU)
        row -= (row >= 96) ? 96 : 0;
        const float v = hr[row * RPITCH + elane];  // lane-consecutive, 2-way free
        const v2f vv = {v, v};
#pragma unroll
        for (int m = 0; m < 8; ++m) {
          const int c0 = j - 2 * m;            // compile-time
          if (c0 >= 0 && c0 < 32) {
            const v2f kc = {gc(c0), gc(c0 - 1)};
            acc2[m] = __builtin_elementwise_fma(vv, kc, acc2[m]);
          }
        }
      }
#pragma unroll
      for (int p = 0; p < 16; ++p) {
        const float a = (p & 1) ? acc2[p >> 1].y : acc2[p >> 1].x;
        const size_t ga = base + (size_t)(y0 + t0 + p) * W_ + x0 + elane;
        // expm1(log(1+ins) + ln2*a) == (1+ins)*exp2(a) - 1
        float r = (1.f + insv[p]) * __builtin_amdgcn_exp2f(a) - 1.f;
        out[ga] = fminf(fmaxf(r, 0.f), 1.f);
      }
    }
    __syncthreads();   // B: h-blur sd reads done before next stage overwrites
  }
}

extern "C" void kernel_launch(void* const* d_in, const int* in_sizes, int n_in,
                              void* d_out, int out_size, void* d_ws, size_t ws_size,
                              hipStream_t stream) {
  const float* bg  = (const float*)d_in[0];
  const float* ins = (const float*)d_in[1];
  float* out = (float*)d_out;
  retinex_roll<<<dim3(8, 2, NIMG), dim3(256), 0, stream>>>(bg, ins, out);
}

// Round 9
// 154.116 us; speedup vs baseline: 1.0065x; 1.0065x over previous
//
#include <hip/hip_runtime.h>

// retinex_synthesis, SINGLE-kernel rolling separable blur.
// out = clip((1+ins)*exp2(blur(log2(1+bg) - log2(1+ins))) - 1, 0, 1)
//
// R14 = FUSED phase 2: every thread does h-blur(k) AND emit(k-2) in one
// phase. R13 post-mortem: wave-specialized roles = SIMD-specialized roles
// (wave i of every block lands on SIMD i), so h-SIMDs idled at the barrier
// while emit-SIMDs ground exp2/stores -- VALUBusy fell to 31% with no time
// win. Fusion keeps R13's validated lag-2 ring disjointness but restores
// identical per-wave work (zero imbalance) and mixed pipes on every SIMD.
//   emit(k-2) reads ring rows [32k-79, 32k-18]  (≡ [17,78] mod 96)
//   h-blur(k) writes         [32k-15, 32k+16]  (≡ [81,95]∪[0,16] mod 96)
// -> disjoint within the phase; emit(k-2) reads vs h-blur(k+1) writes
// separated by barriers B(k)+A(k+1). __syncthreads everywhere (R9: custom
// barrier neutral; R12: custom barrier + divergence aborted).
//
// Per iter k (k=0..9): stage(k) [k<=8] + prefetch(k+1) [k<=7]; barA;
// h-blur(k) [k<=8] + emit(k-2) [k>=2]; barB.
// Geometry (proven): 64w x 256t strips, grid 8*2*48 = 768 = 3 blocks/CU.
// LDS = sd 12.8KB + ring 96x68x4 = 26.1KB = 38.9KB -> 3 blocks/CU.
// Blur FMAs packed (R11): v_pk_fma_f32 via <2 x float> fma, zero-padded
// compile-time coefficient pairs, per-output accumulation order preserved.
// log2 domain (R11): raw v_log_f32/v_exp_f32, no scale muls.
// Ring mod-96 via SALU conditional subtracts; emit row base wave-uniform
// (readfirstlane eg). Epilogue ins loads issued before v-blur (L2-hot).

constexpr int W_ = 512, H_ = 512, NIMG = 48;
constexpr int SPITCH = 100;  // staging pitch: 96 cols + 4; 25 slots, 25%8==1
constexpr int RPITCH = 68;   // ring pitch: 64 cols + 4
constexpr int RSLOTS = 96;   // ring rows (logical row mod 96)

typedef float v2f __attribute__((ext_vector_type(2)));

__device__ constexpr float G[31] = {
    8.8805851e-04f, 1.5861066e-03f, 2.7217699e-03f, 4.4874399e-03f,
    7.1084368e-03f, 1.0818767e-02f, 1.5820117e-02f, 2.2226435e-02f,
    3.0002549e-02f, 3.8911209e-02f, 4.8486352e-02f, 5.8048702e-02f,
    6.6771901e-02f, 7.3794364e-02f, 7.8357552e-02f, 7.9940480e-02f,
    7.8357552e-02f, 7.3794364e-02f, 6.6771901e-02f, 5.8048702e-02f,
    4.8486352e-02f, 3.8911209e-02f, 3.0002549e-02f, 2.2226435e-02f,
    1.5820117e-02f, 1.0818767e-02f, 7.1084368e-03f, 4.4874399e-03f,
    2.7217699e-03f, 1.5861066e-03f, 8.8805851e-04f};

// Zero-padded coefficient: compile-time c -> literal (0 outside [0,31)).
__device__ constexpr float gc(int c) { return (c >= 0 && c < 31) ? G[c] : 0.f; }

__global__ __launch_bounds__(256, 3) void retinex_roll(const float* __restrict__ bg,
                                                       const float* __restrict__ ins,
                                                       float* __restrict__ out) {
  __shared__ __align__(16) float sd[32 * SPITCH];     // 12,800 B: staged d chunk
  __shared__ __align__(16) float hr[RSLOTS * RPITCH]; // 26,112 B: h-blurred ring

  const int tid  = threadIdx.x;
  const int lane = tid & 63;
  const int x0 = blockIdx.x * 64;
  const int y0 = blockIdx.y * 256;
  const size_t base = (size_t)blockIdx.z * (size_t)(H_ * W_);

  // Staging geometry (k-invariant): 768 float4 items = 32 rows x 24 slots.
  int sr[3], sc[3], gx[3]; bool okx[3];
#pragma unroll
  for (int s = 0; s < 3; ++s) {
    const int item = tid + 256 * s;
    sr[s] = item / 24;
    sc[s] = item - 24 * sr[s];
    gx[s] = x0 - 16 + 4 * sc[s];          // float4-aligned; OOB is whole-float4
    okx[s] = (unsigned)gx[s] < (unsigned)W_;
  }
  const int hrow = tid >> 3;              // h-blur: staged row 0..31
  const int hcg  = tid & 7;               // h-blur: col group (8 cols each)
  // emit row-group 0..3 — wave-uniform: force scalar so ring addressing is SALU
  const int eg = __builtin_amdgcn_readfirstlane(tid >> 6);

  // Initial prefetch: chunk 0 = rows y0-15 .. y0+16.
  float4 pb[3], pn[3];
#pragma unroll
  for (int s = 0; s < 3; ++s) {
    const int gy = y0 - 15 + sr[s];
    pb[s] = make_float4(0.f, 0.f, 0.f, 0.f);
    pn[s] = pb[s];
    if (okx[s] && (unsigned)gy < (unsigned)H_) {
      const size_t a = base + (size_t)gy * W_ + gx[s];
      pb[s] = *(const float4*)(bg + a);
      pn[s] = *(const float4*)(ins + a);
    }
  }

#pragma unroll 1
  for (int k = 0; k < 10; ++k) {
    // ---- P1: stage chunk k: d2 = log2(1+bg)-log2(1+ins).
    if (k <= 8) {
#pragma unroll
      for (int s = 0; s < 3; ++s) {
        float4 v;
        v.x = __builtin_amdgcn_logf(1.f + pb[s].x) - __builtin_amdgcn_logf(1.f + pn[s].x);
        v.y = __builtin_amdgcn_logf(1.f + pb[s].y) - __builtin_amdgcn_logf(1.f + pn[s].y);
        v.z = __builtin_amdgcn_logf(1.f + pb[s].z) - __builtin_amdgcn_logf(1.f + pn[s].z);
        v.w = __builtin_amdgcn_logf(1.f + pb[s].w) - __builtin_amdgcn_logf(1.f + pn[s].w);
        *(float4*)(sd + sr[s] * SPITCH + 4 * sc[s]) = v;   // slot%8=(sr+sc)%8
      }
    }
    // ---- Prefetch chunk k+1 (in flight until next iteration's stage).
    if (k <= 7) {
#pragma unroll
      for (int s = 0; s < 3; ++s) {
        const int gy = y0 + 32 * (k + 1) - 15 + sr[s];
        float4 b0 = make_float4(0.f, 0.f, 0.f, 0.f), n0 = b0;
        if (okx[s] && (unsigned)gy < (unsigned)H_) {
          const size_t a = base + (size_t)gy * W_ + gx[s];
          b0 = *(const float4*)(bg + a);
          n0 = *(const float4*)(ins + a);
        }
        pb[s] = b0; pn[s] = n0;
      }
    }
    __syncthreads();   // A: sd ready; orders prev emit ring reads vs h-blur writes

    // ---- P2a: h-blur(k): staged row hrow, cols 8*hcg..+7 -> ring.
    if (k <= 8) {
      v2f o2[4];
#pragma unroll
      for (int m = 0; m < 4; ++m) o2[m] = (v2f){0.f, 0.f};
      const float4* p4 = (const float4*)(sd + hrow * SPITCH) + 2 * hcg;
#pragma unroll
      for (int q = 0; q < 10; ++q) {       // slot%8=(hrow+2hcg+q)%8: balanced
        const float4 v = p4[q];
        const float w4[4] = {v.x, v.y, v.z, v.w};
#pragma unroll
        for (int t = 0; t < 4; ++t) {
          const int pos = 4 * q + t;       // window index: sd col 8*hcg + pos
          const v2f vv = {w4[t], w4[t]};
#pragma unroll
          for (int m = 0; m < 4; ++m) {
            const int c0 = pos - 1 - 2 * m;   // compile-time
            if (c0 >= 0 && c0 < 32) {
              const v2f kc = {gc(c0), gc(c0 - 1)};
              o2[m] = __builtin_elementwise_fma(vv, kc, o2[m]);
            }
          }
        }
      }
      // slot = (32k - 15 + hrow) mod 96 via conditional subtracts.
      int u = 32 * k + 81 + hrow;          // [81, 368]
      u -= (u >= 192) ? 192 : 0;           // [0, 191]
      u -= (u >= 96) ? 96 : 0;             // [0, 95]
      float* dst = hr + u * RPITCH + 8 * hcg;
      *(float4*)(dst)     = make_float4(o2[0].x, o2[0].y, o2[1].x, o2[1].y);
      *(float4*)(dst + 4) = make_float4(o2[2].x, o2[2].y, o2[3].x, o2[3].y);
    }
    // ---- P2b: emit(k-2): rows [32(k-2), 32(k-2)+32) from ring + epilogue.
    //      Reads ring rows disjoint from P2a's writes (see header audit).
    if (k >= 2) {
      const int t0 = 32 * (k - 2) + 8 * eg;    // block-relative first row (scalar)
      int eb = t0 + 81;                        // (t0-15) mod 96: [81, 329]
      eb -= (eb >= 192) ? 192 : 0;
      eb -= (eb >= 96) ? 96 : 0;               // [0, 95]
      // Epilogue ins loads issued early; latency hides under v-blur.
      float insv[8];
#pragma unroll
      for (int p = 0; p < 8; ++p)
        insv[p] = ins[base + (size_t)(y0 + t0 + p) * W_ + x0 + lane];
      v2f acc2[4];
#pragma unroll
      for (int m = 0; m < 4; ++m) acc2[m] = (v2f){0.f, 0.f};
#pragma unroll
      for (int j = 0; j < 38; ++j) {           // h-rows t0-15 .. t0+22
        int row = eb + j;                      // scalar (SALU)
        row -= (row >= 96) ? 96 : 0;
        const float v = hr[row * RPITCH + lane];  // lane-consecutive, 2-way free
        const v2f vv = {v, v};
#pragma unroll
        for (int m = 0; m < 4; ++m) {
          const int c0 = j - 2 * m;            // compile-time
          if (c0 >= 0 && c0 < 32) {
            const v2f kc = {gc(c0), gc(c0 - 1)};
            acc2[m] = __builtin_elementwise_fma(vv, kc, acc2[m]);
          }
        }
      }
#pragma unroll
      for (int p = 0; p < 8; ++p) {
        const float a = (p & 1) ? acc2[p >> 1].y : acc2[p >> 1].x;
        const size_t ga = base + (size_t)(y0 + t0 + p) * W_ + x0 + lane;
        // expm1(log(1+ins) + ln2*a) == (1+ins)*exp2(a) - 1
        float r = (1.f + insv[p]) * __builtin_amdgcn_exp2f(a) - 1.f;
        out[ga] = fminf(fmaxf(r, 0.f), 1.f);
      }
    }
    __syncthreads();   // B: h-blur sd reads done before next stage overwrites;
                       //    emit ring reads done before next h-blur writes
  }
}

extern "C" void kernel_launch(void* const* d_in, const int* in_sizes, int n_in,
                              void* d_out, int out_size, void* d_ws, size_t ws_size,
                              hipStream_t stream) {
  const float* bg  = (const float*)d_in[0];
  const float* ins = (const float*)d_in[1];
  float* out = (float*)d_out;
  retinex_roll<<<dim3(8, 2, NIMG), dim3(256), 0, stream>>>(bg, ins, out);
}

// Round 10
// 153.122 us; speedup vs baseline: 1.0130x; 1.0065x over previous
//
#include <hip/hip_runtime.h>

// retinex_synthesis, SINGLE-kernel rolling separable blur.
// out = clip((1+ins)*exp2(blur(log2(1+bg) - log2(1+ins))) - 1, 0, 1)
//
// R15 = R11 VERBATIM (best measured, 56us) + LDS pitch fix.
// Scheduling arc is closed: R8 merge (-), R9 lds-barrier (0), R10 occupancy
// (0), R13 wave-split (-), R14 fusion (0). Only WORK REDUCTION has ever
// helped (R7 streaming, R11 packed FMA). Busiest pipe in R11: LDS at ~52%
// (ops ~18us + SQ_LDS_BANK_CONFLICT 6.75M = ~26K cyc/CU = ~11us stall).
// Conflict source located analytically: SPITCH=100, RPITCH=68 give
// bank-group = (hrow + 2hcg + q) mod 8 for h-blur b128 reads -- 2hcg is
// EVEN, so 64 lanes hit only 4 of 8 four-bank groups (16 lanes/group =
// 2x serialization vs the 8-lane wave64-b128 floor). Ring b128 writes
// ((17slot + 2hcg) mod 8) have the same even-parity defect.
// Fix: SPITCH 108 (group = 3*hrow + 2hcg + q: odd multiplier -> exactly
// 8 lanes/group, uniform), RPITCH 76 (group = 3*slot + 2hcg: uniform;
// emit b32 reads become (12row+lane) mod 32: still free 2-way).
// LDS = 32*108*4 + 64*76*4 = 13,824 + 19,456 = 33,280 B -> 3 blocks/CU.
//
// Geometry (proven): 64w x 256t strips, grid 8*2*48 = 768 = 3 blocks/CU.
// 9 chunks of 32 rows: stage chunk k (rows [32k-15,32k+17), 96 cols) from
// PREFETCHED regs -> LDS; prefetch k+1; [lgkm bar]; h-blur -> 64-row ring;
// [lgkm bar]; emit rows [32(k-1),32k) v-blur + fused epilogue.
// Barriers are LDS-only (lgkmcnt(0)+s_barrier, R9-proven): all cross-wave
// hazards are LDS; prefetch stays in flight across barriers.
// Blur FMAs packed (R11): v_pk_fma_f32 via <2 x float> fma, zero-padded
// compile-time coefficient pairs, per-output accumulation order preserved.
// log2 domain (R11): raw v_log_f32/v_exp_f32, no scale muls.
// Emit ring addressing wave-uniform via readfirstlane -> SALU.

constexpr int W_ = 512, H_ = 512, NIMG = 48;
constexpr int SPITCH = 108;  // staging pitch: 96 cols + 12; 27 slots (odd*4)
                             // -> h-read group (3*hrow+2hcg+q)%8 uniform
constexpr int RPITCH = 76;   // ring pitch: 64 cols + 12; 19 slots (odd*4)
                             // -> ring-write group (3*slot+2hcg)%8 uniform

typedef float v2f __attribute__((ext_vector_type(2)));

// LDS-only barrier: cross-wave LDS visibility needs lgkmcnt(0) commit, but
// NOT vmcnt drain (that's the __syncthreads tax this kernel avoids).
#define LDS_BARRIER()                                      \
  do {                                                     \
    asm volatile("" ::: "memory");                         \
    asm volatile("s_waitcnt lgkmcnt(0)" ::: "memory");     \
    __builtin_amdgcn_s_barrier();                          \
    asm volatile("" ::: "memory");                         \
  } while (0)

__device__ constexpr float G[31] = {
    8.8805851e-04f, 1.5861066e-03f, 2.7217699e-03f, 4.4874399e-03f,
    7.1084368e-03f, 1.0818767e-02f, 1.5820117e-02f, 2.2226435e-02f,
    3.0002549e-02f, 3.8911209e-02f, 4.8486352e-02f, 5.8048702e-02f,
    6.6771901e-02f, 7.3794364e-02f, 7.8357552e-02f, 7.9940480e-02f,
    7.8357552e-02f, 7.3794364e-02f, 6.6771901e-02f, 5.8048702e-02f,
    4.8486352e-02f, 3.8911209e-02f, 3.0002549e-02f, 2.2226435e-02f,
    1.5820117e-02f, 1.0818767e-02f, 7.1084368e-03f, 4.4874399e-03f,
    2.7217699e-03f, 1.5861066e-03f, 8.8805851e-04f};

// Zero-padded coefficient: compile-time c -> literal (0 outside [0,31)).
__device__ constexpr float gc(int c) { return (c >= 0 && c < 31) ? G[c] : 0.f; }

__global__ __launch_bounds__(256, 3) void retinex_roll(const float* __restrict__ bg,
                                                       const float* __restrict__ ins,
                                                       float* __restrict__ out) {
  __shared__ __align__(16) float sd[32 * SPITCH];  // 13,824 B: staged d chunk
  __shared__ __align__(16) float hr[64 * RPITCH];  // 19,456 B: h-blurred ring

  const int tid  = threadIdx.x;
  const int lane = tid & 63;
  const int x0 = blockIdx.x * 64;
  const int y0 = blockIdx.y * 256;
  const size_t base = (size_t)blockIdx.z * (size_t)(H_ * W_);

  // Staging geometry (k-invariant): 768 float4 items = 32 rows x 24 slots.
  int sr[3], sc[3], gx[3]; bool okx[3];
#pragma unroll
  for (int s = 0; s < 3; ++s) {
    const int item = tid + 256 * s;
    sr[s] = item / 24;
    sc[s] = item - 24 * sr[s];
    gx[s] = x0 - 16 + 4 * sc[s];          // float4-aligned; OOB is whole-float4
    okx[s] = (unsigned)gx[s] < (unsigned)W_;
  }
  const int hrow = tid >> 3;              // h-blur: staged row 0..31
  const int hcg  = tid & 7;               // h-blur: col group (8 cols each)
  // emit row-group 0..3 — wave-uniform: force scalar so ring addressing is SALU
  const int eg = __builtin_amdgcn_readfirstlane(tid >> 6);

  // Initial prefetch: chunk 0 = rows y0-15 .. y0+16.
  float4 pb[3], pn[3];
#pragma unroll
  for (int s = 0; s < 3; ++s) {
    const int gy = y0 - 15 + sr[s];
    pb[s] = make_float4(0.f, 0.f, 0.f, 0.f);
    pn[s] = pb[s];
    if (okx[s] && (unsigned)gy < (unsigned)H_) {
      const size_t a = base + (size_t)gy * W_ + gx[s];
      pb[s] = *(const float4*)(bg + a);
      pn[s] = *(const float4*)(ins + a);
    }
  }

#pragma unroll 1
  for (int k = 0; k < 9; ++k) {
    // ---- Stage chunk k from prefetched regs: d2 = log2(1+bg)-log2(1+ins).
#pragma unroll
    for (int s = 0; s < 3; ++s) {
      float4 v;
      v.x = __builtin_amdgcn_logf(1.f + pb[s].x) - __builtin_amdgcn_logf(1.f + pn[s].x);
      v.y = __builtin_amdgcn_logf(1.f + pb[s].y) - __builtin_amdgcn_logf(1.f + pn[s].y);
      v.z = __builtin_amdgcn_logf(1.f + pb[s].z) - __builtin_amdgcn_logf(1.f + pn[s].z);
      v.w = __builtin_amdgcn_logf(1.f + pb[s].w) - __builtin_amdgcn_logf(1.f + pn[s].w);
      *(float4*)(sd + sr[s] * SPITCH + 4 * sc[s]) = v;   // group (3sr+sc)%8: uniform
    }
    // ---- Prefetch chunk k+1; loads stay in flight until next iteration's
    //      stage (vmcnt wait at first USE, not at the barriers).
    if (k < 8) {
#pragma unroll
      for (int s = 0; s < 3; ++s) {
        const int gy = y0 + 32 * (k + 1) - 15 + sr[s];
        float4 b0 = make_float4(0.f, 0.f, 0.f, 0.f), n0 = b0;
        if (okx[s] && (unsigned)gy < (unsigned)H_) {
          const size_t a = base + (size_t)gy * W_ + gx[s];
          b0 = *(const float4*)(bg + a);
          n0 = *(const float4*)(ins + a);
        }
        pb[s] = b0; pn[s] = n0;
      }
    }
    LDS_BARRIER();   // A: sd ready; also orders prev emit's hr reads vs h-blur writes

    // ---- H-blur staged row `hrow`, cols 8*hcg..8*hcg+7 -> ring.
    //      PACKED: output pairs (e,e+1) accumulate via v_pk_fma_f32.
    {
      v2f o2[4];
#pragma unroll
      for (int m = 0; m < 4; ++m) o2[m] = (v2f){0.f, 0.f};
      const float4* p4 = (const float4*)(sd + hrow * SPITCH) + 2 * hcg;
#pragma unroll
      for (int q = 0; q < 10; ++q) {       // group (3hrow+2hcg+q)%8: 8 lanes/group
        const float4 v = p4[q];
        const float w4[4] = {v.x, v.y, v.z, v.w};
#pragma unroll
        for (int t = 0; t < 4; ++t) {
          const int pos = 4 * q + t;       // window index: sd col 8*hcg + pos
          const v2f vv = {w4[t], w4[t]};
#pragma unroll
          for (int m = 0; m < 4; ++m) {
            const int c0 = pos - 1 - 2 * m;   // compile-time
            if (c0 >= 0 && c0 < 32) {
              const v2f kc = {gc(c0), gc(c0 - 1)};
              o2[m] = __builtin_elementwise_fma(vv, kc, o2[m]);
            }
          }
        }
      }
      const int slot = (32 * k - 15 + hrow + 128) & 63;  // logical row 32k-15+hrow
      float* dst = hr + slot * RPITCH + 8 * hcg;         // group (3slot+2hcg)%8: uniform
      *(float4*)(dst)     = make_float4(o2[0].x, o2[0].y, o2[1].x, o2[1].y);
      *(float4*)(dst + 4) = make_float4(o2[2].x, o2[2].y, o2[3].x, o2[3].y);
    }
    LDS_BARRIER();   // B: ring rows for this chunk ready

    // ---- Emit output rows [32(k-1), 32k): v-blur from ring + epilogue.
    if (k >= 1) {
      const int t0 = 32 * (k - 1) + 8 * eg;    // block-relative first output row
      // Issue epilogue ins loads NOW (L2-hot, staged ~1 chunk ago); their
      // latency hides under the 38-step v-blur. Same phase -> no spill.
      float insv[8];
#pragma unroll
      for (int p = 0; p < 8; ++p)
        insv[p] = ins[base + (size_t)(y0 + t0 + p) * W_ + x0 + lane];
      v2f acc2[4];
#pragma unroll
      for (int m = 0; m < 4; ++m) acc2[m] = (v2f){0.f, 0.f};
#pragma unroll
      for (int j = 0; j < 38; ++j) {
        const int row = (t0 - 15 + j + 128) & 63;        // scalar (SALU)
        const float v = hr[row * RPITCH + lane];         // (12row+lane)%32: 2-way free
        const v2f vv = {v, v};
#pragma unroll
        for (int m = 0; m < 4; ++m) {
          const int c0 = j - 2 * m;            // compile-time
          if (c0 >= 0 && c0 < 32) {
            const v2f kc = {gc(c0), gc(c0 - 1)};
            acc2[m] = __builtin_elementwise_fma(vv, kc, acc2[m]);
          }
        }
      }
#pragma unroll
      for (int p = 0; p < 8; ++p) {
        const float a = (p & 1) ? acc2[p >> 1].y : acc2[p >> 1].x;
        const size_t ga = base + (size_t)(y0 + t0 + p) * W_ + x0 + lane;
        // expm1(log(1+ins) + ln2*a) == (1+ins)*exp2(a) - 1
        float r = (1.f + insv[p]) * __builtin_amdgcn_exp2f(a) - 1.f;
        out[ga] = fminf(fmaxf(r, 0.f), 1.f);
      }
    }
  }
}

extern "C" void kernel_launch(void* const* d_in, const int* in_sizes, int n_in,
                              void* d_out, int out_size, void* d_ws, size_t ws_size,
                              hipStream_t stream) {
  const float* bg  = (const float*)d_in[0];
  const float* ins = (const float*)d_in[1];
  float* out = (float*)d_out;
  retinex_roll<<<dim3(8, 2, NIMG), dim3(256), 0, stream>>>(bg, ins, out);
}

// Round 12
// 151.949 us; speedup vs baseline: 1.0208x; 1.0077x over previous
//
#include <hip/hip_runtime.h>

// retinex_synthesis, SINGLE-kernel rolling separable blur.
// out = clip((1+ins)*exp2(blur(log2(1+bg) - log2(1+ins))) - 1, 0, 1)
//
// R16 (resubmit; previous round died on container acquisition, kernel
// never ran) = R11 base (best measured: 56us disp / 151.9us harness)
// with emit restructured to 64 ROWS EVERY OTHER CHUNK (16 rows/thread).
// Arc status: scheduling closed (R8-,R9 0,R10 0,R13-,R14 0); bank
// conflicts off critical path (R13: 6.75M->4.26M, time flat; R15 pitch
// fix: time flat). Only WORK REDUCTION moves time (R7 -7us, R11 -7us).
// This round's reduction, all in the emit phase:
//   - emit LDS reads: 8 phases x 38 b32 = 304/thread -> 4 x 46 = 184
//     (window 46 rows per 16 outputs vs 38 per 8)
//   - ring mod: 128 slots -> (r+128)&127, frees the SALU subtract chains
//   - 4 insv/store batches instead of 8 (addressing amortized 2x)
// Ring-128 hazard audit (emit at k in {3,5,7,9}, t0b = 32(k-3)):
//   emit reads  logical [32k-111, 32k-50]  == rel slots [17..78]
//   h(k) writes logical [32k-15,  32k+16]  == rel slots [113..127]U[0..16]
//   -> disjoint in-phase; oldest-needed == oldest-live (exact 128 fit);
//   newest-needed (32k-50) written by h(k-2), two barriers earlier;
//   emit(k) reads vs h(k+1) writes (rel [17..48]) separated by barA(k+1).
// Coverage: k=3:rows 0-63, k=5:64-127, k=7:128-191, k=9:192-255.
//
// Geometry (proven): 64w x 256t strips, grid 8*2*48 = 768 = 3 blocks/CU.
// Iter k=0..9: stage(k) [k<=8] + prefetch(k+1) [k<=7]; barA; h(k) [k<=8];
// barB; emit [k odd >=3]. Barriers LDS-only (R9-proven neutral+safe).
// Packed blur FMAs (R11): v_pk_fma_f32, zero-padded compile-time coeff
// pairs, per-output accumulation order preserved. log2 domain (R11).
// LDS = sd 32x100x4 = 12,800 + ring 128x68x4 = 34,816 = 47.6 KB.

constexpr int W_ = 512, H_ = 512, NIMG = 48;
constexpr int SPITCH = 100;  // staging pitch: 96 cols + 4 (R11-proven)
constexpr int RPITCH = 68;   // ring pitch: 64 cols + 4; emit b32 2-way free
constexpr int RSLOTS = 128;  // ring rows; mod-128 is AND

typedef float v2f __attribute__((ext_vector_type(2)));

// LDS-only barrier: cross-wave LDS visibility needs lgkmcnt(0) commit, but
// NOT vmcnt drain; prefetch loads stay in flight across barriers.
#define LDS_BARRIER()                                      \
  do {                                                     \
    asm volatile("" ::: "memory");                         \
    asm volatile("s_waitcnt lgkmcnt(0)" ::: "memory");     \
    __builtin_amdgcn_s_barrier();                          \
    asm volatile("" ::: "memory");                         \
  } while (0)

__device__ constexpr float G[31] = {
    8.8805851e-04f, 1.5861066e-03f, 2.7217699e-03f, 4.4874399e-03f,
    7.1084368e-03f, 1.0818767e-02f, 1.5820117e-02f, 2.2226435e-02f,
    3.0002549e-02f, 3.8911209e-02f, 4.8486352e-02f, 5.8048702e-02f,
    6.6771901e-02f, 7.3794364e-02f, 7.8357552e-02f, 7.9940480e-02f,
    7.8357552e-02f, 7.3794364e-02f, 6.6771901e-02f, 5.8048702e-02f,
    4.8486352e-02f, 3.8911209e-02f, 3.0002549e-02f, 2.2226435e-02f,
    1.5820117e-02f, 1.0818767e-02f, 7.1084368e-03f, 4.4874399e-03f,
    2.7217699e-03f, 1.5861066e-03f, 8.8805851e-04f};

// Zero-padded coefficient: compile-time c -> literal (0 outside [0,31)).
__device__ constexpr float gc(int c) { return (c >= 0 && c < 31) ? G[c] : 0.f; }

__global__ __launch_bounds__(256, 3) void retinex_roll(const float* __restrict__ bg,
                                                       const float* __restrict__ ins,
                                                       float* __restrict__ out) {
  __shared__ __align__(16) float sd[32 * SPITCH];       // 12,800 B: staged d chunk
  __shared__ __align__(16) float hr[RSLOTS * RPITCH];   // 34,816 B: h-blurred ring

  const int tid  = threadIdx.x;
  const int lane = tid & 63;
  const int x0 = blockIdx.x * 64;
  const int y0 = blockIdx.y * 256;
  const size_t base = (size_t)blockIdx.z * (size_t)(H_ * W_);

  // Staging geometry (k-invariant): 768 float4 items = 32 rows x 24 slots.
  int sr[3], sc[3], gx[3]; bool okx[3];
#pragma unroll
  for (int s = 0; s < 3; ++s) {
    const int item = tid + 256 * s;
    sr[s] = item / 24;
    sc[s] = item - 24 * sr[s];
    gx[s] = x0 - 16 + 4 * sc[s];          // float4-aligned; OOB is whole-float4
    okx[s] = (unsigned)gx[s] < (unsigned)W_;
  }
  const int hrow = tid >> 3;              // h-blur: staged row 0..31
  const int hcg  = tid & 7;               // h-blur: col group (8 cols each)
  // emit row-group 0..3 (16 rows each) — wave-uniform -> SALU addressing
  const int eg = __builtin_amdgcn_readfirstlane(tid >> 6);

  // Initial prefetch: chunk 0 = rows y0-15 .. y0+16.
  float4 pb[3], pn[3];
#pragma unroll
  for (int s = 0; s < 3; ++s) {
    const int gy = y0 - 15 + sr[s];
    pb[s] = make_float4(0.f, 0.f, 0.f, 0.f);
    pn[s] = pb[s];
    if (okx[s] && (unsigned)gy < (unsigned)H_) {
      const size_t a = base + (size_t)gy * W_ + gx[s];
      pb[s] = *(const float4*)(bg + a);
      pn[s] = *(const float4*)(ins + a);
    }
  }

#pragma unroll 1
  for (int k = 0; k < 10; ++k) {
    // ---- Stage chunk k from prefetched regs: d2 = log2(1+bg)-log2(1+ins).
    if (k <= 8) {
#pragma unroll
      for (int s = 0; s < 3; ++s) {
        float4 v;
        v.x = __builtin_amdgcn_logf(1.f + pb[s].x) - __builtin_amdgcn_logf(1.f + pn[s].x);
        v.y = __builtin_amdgcn_logf(1.f + pb[s].y) - __builtin_amdgcn_logf(1.f + pn[s].y);
        v.z = __builtin_amdgcn_logf(1.f + pb[s].z) - __builtin_amdgcn_logf(1.f + pn[s].z);
        v.w = __builtin_amdgcn_logf(1.f + pb[s].w) - __builtin_amdgcn_logf(1.f + pn[s].w);
        *(float4*)(sd + sr[s] * SPITCH + 4 * sc[s]) = v;   // slot%8=(sr+sc)%8
      }
    }
    // ---- Prefetch chunk k+1; in flight until next iteration's stage.
    if (k <= 7) {
#pragma unroll
      for (int s = 0; s < 3; ++s) {
        const int gy = y0 + 32 * (k + 1) - 15 + sr[s];
        float4 b0 = make_float4(0.f, 0.f, 0.f, 0.f), n0 = b0;
        if (okx[s] && (unsigned)gy < (unsigned)H_) {
          const size_t a = base + (size_t)gy * W_ + gx[s];
          b0 = *(const float4*)(bg + a);
          n0 = *(const float4*)(ins + a);
        }
        pb[s] = b0; pn[s] = n0;
      }
    }
    LDS_BARRIER();   // A: sd ready; orders prev emit's ring reads vs h writes

    // ---- H-blur staged row `hrow`, cols 8*hcg..8*hcg+7 -> ring.
    if (k <= 8) {
      v2f o2[4];
#pragma unroll
      for (int m = 0; m < 4; ++m) o2[m] = (v2f){0.f, 0.f};
      const float4* p4 = (const float4*)(sd + hrow * SPITCH) + 2 * hcg;
#pragma unroll
      for (int q = 0; q < 10; ++q) {       // slot%8=(hrow+2hcg+q)%8: balanced
        const float4 v = p4[q];
        const float w4[4] = {v.x, v.y, v.z, v.w};
#pragma unroll
        for (int t = 0; t < 4; ++t) {
          const int pos = 4 * q + t;       // window index: sd col 8*hcg + pos
          const v2f vv = {w4[t], w4[t]};
#pragma unroll
          for (int m = 0; m < 4; ++m) {
            const int c0 = pos - 1 - 2 * m;   // compile-time
            if (c0 >= 0 && c0 < 32) {
              const v2f kc = {gc(c0), gc(c0 - 1)};
              o2[m] = __builtin_elementwise_fma(vv, kc, o2[m]);
            }
          }
        }
      }
      const int slot = (32 * k - 15 + hrow + 128) & 127;  // logical row mod 128
      float* dst = hr + slot * RPITCH + 8 * hcg;
      *(float4*)(dst)     = make_float4(o2[0].x, o2[0].y, o2[1].x, o2[1].y);
      *(float4*)(dst + 4) = make_float4(o2[2].x, o2[2].y, o2[3].x, o2[3].y);
    }
    LDS_BARRIER();   // B: ring rows for this chunk committed

    // ---- Emit 64 rows [32(k-3), 32(k-3)+64) at k = 3,5,7,9.
    if ((k >= 3) && (k & 1)) {
      const int t0 = 32 * (k - 3) + 16 * eg;   // first output row (scalar)
      // Epilogue ins loads issued early; latency hides under v-blur.
      float insv[16];
#pragma unroll
      for (int p = 0; p < 16; ++p)
        insv[p] = ins[base + (size_t)(y0 + t0 + p) * W_ + x0 + lane];
      v2f acc2[8];
#pragma unroll
      for (int m = 0; m < 8; ++m) acc2[m] = (v2f){0.f, 0.f};
#pragma unroll
      for (int j = 0; j < 46; ++j) {           // h-rows t0-15 .. t0+30
        const int row = (t0 - 15 + j + 128) & 127;       // scalar (SALU)
        const float v = hr[row * RPITCH + lane];         // 2-way free
        const v2f vv = {v, v};
#pragma unroll
        for (int m = 0; m < 8; ++m) {
          const int c0 = j - 2 * m;            // compile-time
          if (c0 >= 0 && c0 < 32) {
            const v2f kc = {gc(c0), gc(c0 - 1)};
            acc2[m] = __builtin_elementwise_fma(vv, kc, acc2[m]);
          }
        }
      }
#pragma unroll
      for (int p = 0; p < 16; ++p) {
        const float a = (p & 1) ? acc2[p >> 1].y : acc2[p >> 1].x;
        const size_t ga = base + (size_t)(y0 + t0 + p) * W_ + x0 + lane;
        // expm1(log(1+ins) + ln2*a) == (1+ins)*exp2(a) - 1
        float r = (1.f + insv[p]) * __builtin_amdgcn_exp2f(a) - 1.f;
        out[ga] = fminf(fmaxf(r, 0.f), 1.f);
      }
    }
  }
}

extern "C" void kernel_launch(void* const* d_in, const int* in_sizes, int n_in,
                              void* d_out, int out_size, void* d_ws, size_t ws_size,
                              hipStream_t stream) {
  const float* bg  = (const float*)d_in[0];
  const float* ins = (const float*)d_in[1];
  float* out = (float*)d_out;
  retinex_roll<<<dim3(8, 2, NIMG), dim3(256), 0, stream>>>(bg, ins, out);
}